// Round 1
// baseline (364.984 us; speedup 1.0000x reference)
//
#include <hip/hip_runtime.h>
#include <hip/hip_bf16.h>
#include <math.h>

// Router: patch (N,32,8,8) f32, keys (16,32) f32 (rows unit-norm), 3 scalars.
// out (N,16) f32.
// Memory-bound: 256 MiB patch read dominates. One block = 8 patches.

#define C 32
#define HW 64        // 8*8 spatial
#define E 16         // experts
#define PPB 8        // patches per block
#define LOG_E16 2.7725887222397811f  // ln(16)

__device__ __forceinline__ float rsum16(float x) {
    #pragma unroll
    for (int m = 1; m < 16; m <<= 1) x += __shfl_xor(x, m, 16);
    return x;
}
__device__ __forceinline__ float rmax16(float x) {
    #pragma unroll
    for (int m = 1; m < 16; m <<= 1) x = fmaxf(x, __shfl_xor(x, m, 16));
    return x;
}

__global__ __launch_bounds__(256) void router_kernel(
    const float* __restrict__ patch, const float* __restrict__ keys,
    const float* __restrict__ p_temp, const float* __restrict__ p_beta,
    const float* __restrict__ p_thr, float* __restrict__ out, int N)
{
    __shared__ float lds_emb[PPB * 33];   // +1 pad per patch row
    __shared__ float lds_keys[E * 33];    // +1 pad: bank = (e + c) % 32

    const int t = threadIdx.x;
    const int block0 = blockIdx.x * PPB;

    // stage keys (512 floats) into padded LDS
    for (int i = t; i < E * C; i += 256)
        lds_keys[(i >> 5) * 33 + (i & 31)] = keys[i];

    // ---- Phase 1: per-(patch,channel) spatial mean; per-patch L2 norm ----
    const int p = t >> 5;        // 0..7
    const int c = t & 31;        // channel
    const int patch_idx = block0 + p;
    float emb = 0.0f;
    if (patch_idx < N) {   // uniform across each 32-lane group
        const float4* base = (const float4*)patch + (size_t)patch_idx * (C * HW / 4) + c * (HW / 4);
        float4 acc = make_float4(0.f, 0.f, 0.f, 0.f);
        #pragma unroll
        for (int j = 0; j < HW / 4; ++j) {
            float4 v = base[j];
            acc.x += v.x; acc.y += v.y; acc.z += v.z; acc.w += v.w;
        }
        float mean = ((acc.x + acc.y) + (acc.z + acc.w)) * (1.0f / 64.0f);
        // L2 norm across the 32 channels (one half-wave = one patch)
        float sq = mean * mean;
        #pragma unroll
        for (int m = 1; m < 32; m <<= 1) sq += __shfl_xor(sq, m, 32);
        float inv = 1.0f / fmaxf(sqrtf(sq), 1e-12f);
        emb = mean * inv;
    }
    lds_emb[p * 33 + c] = emb;
    __syncthreads();

    // ---- Phase 3: 16 lanes per patch, lane = expert ----
    if (t < PPB * E) {
        const int q = t >> 4;     // patch slot 0..7
        const int e = t & 15;     // expert
        const int pidx = block0 + q;
        if (pidx < N) {   // uniform across each 16-lane group
            float logit = 0.0f;
            #pragma unroll
            for (int cc = 0; cc < C; ++cc)
                logit += lds_emb[q * 33 + cc] * lds_keys[e * 33 + cc];

            const float temp = p_temp[0];
            const float beta = p_beta[0];
            const float thr  = p_thr[0];

            float s = logit / temp + 1e-8f;

            // softmax over the 16 lanes
            float smax = rmax16(s);
            float ex = expf(s - smax);
            float esum = rsum16(ex);
            float w = ex / esum;

            // stats
            float wsum = rsum16(w);
            float mean_w = wsum * (1.0f / 16.0f);
            float d = w - mean_w;
            float var = rsum16(d * d) * (1.0f / 15.0f);   // ddof=1
            float std_w = sqrtf(var);
            float entropy = -rsum16(w * logf(w + 1e-18f));

            // descending bitonic sort of w across the 16 lanes
            float v = w;
            const int lane16 = e;
            #pragma unroll
            for (int k = 2; k <= 16; k <<= 1) {
                #pragma unroll
                for (int j = k >> 1; j > 0; j >>= 1) {
                    float o = __shfl_xor(v, j, 16);
                    bool lower = (lane16 & j) == 0;
                    bool asc = (lane16 & k) != 0;    // flipped -> final descending
                    float lo = fminf(v, o), hi = fmaxf(v, o);
                    v = (asc == lower) ? lo : hi;
                }
            }
            float s0 = __shfl(v, 0, 16);
            float s1 = __shfl(v, 1, 16);
            float s2 = __shfl(v, 2, 16);
            float s3 = __shfl(v, 3, 16);
            float s4 = __shfl(v, 4, 16);

            // adaptive threshold
            float max_c = 1.0f - s0;
            float ent_c = 1.0f - entropy * (1.0f / LOG_E16);
            float mean_rest = 0.25f * ((s1 + s2) + (s3 + s4));
            float gap = (s0 - mean_rest) / (s0 + 1e-8f);
            gap = fminf(fmaxf(gap, 0.0f), 1.0f);
            float af = 0.4f * max_c + 0.3f * ent_c + 0.3f * gap;
            float adaptive = thr * (0.5f + af);
            float min_thr = fmaxf(0.05f, mean_w - 0.5f * std_w);
            float max_thr = fminf(0.7f, s0 - 0.1f * std_w);
            adaptive = fminf(fmaxf(adaptive, min_thr), max_thr);
            adaptive = fminf(adaptive, s3 * 0.9f);

            // soft mask + renormalize
            float z = (beta + 1e-8f) * (w - adaptive);
            float mask = 1.0f / (1.0f + expf(-z));
            float wf = w * mask;
            float sw = rsum16(wf);
            wf = wf / fmaxf(sw, 1e-8f);

            out[(size_t)pidx * E + e] = wf;
        }
    }
}

extern "C" void kernel_launch(void* const* d_in, const int* in_sizes, int n_in,
                              void* d_out, int out_size, void* d_ws, size_t ws_size,
                              hipStream_t stream) {
    const float* patch = (const float*)d_in[0];
    const float* keys  = (const float*)d_in[1];
    const float* lt    = (const float*)d_in[2];
    const float* mb    = (const float*)d_in[3];
    const float* th    = (const float*)d_in[4];
    float* out = (float*)d_out;
    int N = in_sizes[0] / (C * HW);
    int blocks = (N + PPB - 1) / PPB;
    router_kernel<<<blocks, 256, 0, stream>>>(patch, keys, lt, mb, th, out, N);
}

// Round 2
// 364.288 us; speedup vs baseline: 1.0019x; 1.0019x over previous
//
#include <hip/hip_runtime.h>
#include <hip/hip_bf16.h>
#include <math.h>

// Router: patch (N,32,8,8) f32, keys (16,32) f32 (rows unit-norm), 3 scalars.
// out (N,16) f32.  Memory-bound: 256 MiB patch read dominates.
//
// Phase 1 is fully coalesced: one wave-wide float4 load = 1 KB contiguous.
// Lane i of iteration j holds 4 elems of channel (4j + i/16); width-16
// shuffle butterfly produces channel sums. Block = 16 patches (4 per wave).

#define C 32
#define HW 64        // 8*8 spatial
#define E 16         // experts
#define PPW 4        // patches per wave
#define PPB 16       // patches per block (4 waves)
#define LOG_E16 2.7725887222397811f  // ln(16)

__device__ __forceinline__ float rsum16(float x) {
    #pragma unroll
    for (int m = 1; m < 16; m <<= 1) x += __shfl_xor(x, m, 16);
    return x;
}
__device__ __forceinline__ float rmax16(float x) {
    #pragma unroll
    for (int m = 1; m < 16; m <<= 1) x = fmaxf(x, __shfl_xor(x, m, 16));
    return x;
}
__device__ __forceinline__ float rsum64(float x) {
    #pragma unroll
    for (int m = 1; m < 64; m <<= 1) x += __shfl_xor(x, m, 64);
    return x;
}

__global__ __launch_bounds__(256) void router_kernel(
    const float* __restrict__ patch, const float* __restrict__ keys,
    const float* __restrict__ p_temp, const float* __restrict__ p_beta,
    const float* __restrict__ p_thr, float* __restrict__ out, int N)
{
    __shared__ float lds_emb[PPB * 33];   // channel means, +1 pad
    __shared__ float lds_inv[PPB];        // 1/||emb||
    __shared__ float lds_keys[E * 33];    // padded: bank(e,c) = (e+c)%32

    const int t = threadIdx.x;
    const int wave = t >> 6;
    const int lane = t & 63;
    const int block0 = blockIdx.x * PPB;

    // stage keys (512 floats) into padded LDS
    for (int i = t; i < E * C; i += 256)
        lds_keys[(i >> 5) * 33 + (i & 31)] = keys[i];

    // ---- Phase 1: coalesced streaming reduction, 4 patches per wave ----
    #pragma unroll
    for (int pp = 0; pp < PPW; ++pp) {
        const int p = wave * PPW + pp;          // block slot 0..15
        const int pidx = block0 + p;
        if (pidx < N) {                          // wave-uniform
            const float4* base = (const float4*)(patch + (size_t)pidx * (C * HW));
            float sq = 0.0f;
            #pragma unroll
            for (int j = 0; j < 8; ++j) {
                float4 v = base[j * 64 + lane];  // lane-contiguous: 1 KB/instr
                float s = ((v.x + v.y) + (v.z + v.w));
                s = rsum16(s);                   // channel sum (64 elems)
                float mean = s * (1.0f / 64.0f);
                sq += mean * mean;
                if ((lane & 15) == 0)
                    lds_emb[p * 33 + j * 4 + (lane >> 4)] = mean;
            }
            // every channel's mean^2 appears on 16 lanes -> /16
            float tot = rsum64(sq) * (1.0f / 16.0f);
            float inv = 1.0f / fmaxf(sqrtf(tot), 1e-12f);
            if (lane == 0) lds_inv[p] = inv;
        }
    }
    __syncthreads();

    // ---- Phase 3: 16 lanes per patch, lane = expert ----
    {
        const int q = t >> 4;     // patch slot 0..15
        const int e = t & 15;     // expert
        const int pidx = block0 + q;
        if (pidx < N) {           // uniform across each 16-lane group
            const float inv = lds_inv[q];
            float logit = 0.0f;
            #pragma unroll
            for (int cc = 0; cc < C; ++cc)
                logit += lds_emb[q * 33 + cc] * lds_keys[e * 33 + cc];
            logit *= inv;   // normalize emb

            const float temp = p_temp[0];
            const float beta = p_beta[0];
            const float thr  = p_thr[0];

            float s = logit / temp + 1e-8f;

            // softmax over the 16 lanes
            float smax = rmax16(s);
            float ex = expf(s - smax);
            float esum = rsum16(ex);
            float w = ex / esum;

            // stats
            float wsum = rsum16(w);
            float mean_w = wsum * (1.0f / 16.0f);
            float d = w - mean_w;
            float var = rsum16(d * d) * (1.0f / 15.0f);   // ddof=1
            float std_w = sqrtf(var);
            float entropy = -rsum16(w * logf(w + 1e-18f));

            // descending bitonic sort of w across the 16 lanes
            float v = w;
            const int lane16 = e;
            #pragma unroll
            for (int k = 2; k <= 16; k <<= 1) {
                #pragma unroll
                for (int j = k >> 1; j > 0; j >>= 1) {
                    float o = __shfl_xor(v, j, 16);
                    bool lower = (lane16 & j) == 0;
                    bool asc = (lane16 & k) != 0;    // flipped -> final descending
                    float lo = fminf(v, o), hi = fmaxf(v, o);
                    v = (asc == lower) ? lo : hi;
                }
            }
            float s0 = __shfl(v, 0, 16);
            float s1 = __shfl(v, 1, 16);
            float s2 = __shfl(v, 2, 16);
            float s3 = __shfl(v, 3, 16);
            float s4 = __shfl(v, 4, 16);

            // adaptive threshold
            float max_c = 1.0f - s0;
            float ent_c = 1.0f - entropy * (1.0f / LOG_E16);
            float mean_rest = 0.25f * ((s1 + s2) + (s3 + s4));
            float gap = (s0 - mean_rest) / (s0 + 1e-8f);
            gap = fminf(fmaxf(gap, 0.0f), 1.0f);
            float af = 0.4f * max_c + 0.3f * ent_c + 0.3f * gap;
            float adaptive = thr * (0.5f + af);
            float min_thr = fmaxf(0.05f, mean_w - 0.5f * std_w);
            float max_thr = fminf(0.7f, s0 - 0.1f * std_w);
            adaptive = fminf(fmaxf(adaptive, min_thr), max_thr);
            adaptive = fminf(adaptive, s3 * 0.9f);

            // soft mask + renormalize
            float z = (beta + 1e-8f) * (w - adaptive);
            float mask = 1.0f / (1.0f + expf(-z));
            float wf = w * mask;
            float sw = rsum16(wf);
            wf = wf / fmaxf(sw, 1e-8f);

            out[(size_t)pidx * E + e] = wf;
        }
    }
}

extern "C" void kernel_launch(void* const* d_in, const int* in_sizes, int n_in,
                              void* d_out, int out_size, void* d_ws, size_t ws_size,
                              hipStream_t stream) {
    const float* patch = (const float*)d_in[0];
    const float* keys  = (const float*)d_in[1];
    const float* lt    = (const float*)d_in[2];
    const float* mb    = (const float*)d_in[3];
    const float* th    = (const float*)d_in[4];
    float* out = (float*)d_out;
    int N = in_sizes[0] / (C * HW);
    int blocks = (N + PPB - 1) / PPB;
    router_kernel<<<blocks, 256, 0, stream>>>(patch, keys, lt, mb, th, out, N);
}